// Round 22
// baseline (163.573 us; speedup 1.0000x reference)
//
#include <hip/hip_runtime.h>
#include <hip/hip_bf16.h>
#include <stdint.h>

#define NTOK 2048
#define HDIM 1024
#define NEXP 16
#define TOPK 4
#define IR   512
#define ISH  1024
#define RSCALE 2.5f

typedef short bf16x4 __attribute__((ext_vector_type(4)));
typedef short bf16x8 __attribute__((ext_vector_type(8)));
typedef float f32x4  __attribute__((ext_vector_type(4)));

static __device__ __forceinline__ unsigned short f2bf(float f){
  union { float fv; uint32_t u; } v; v.fv = f;
  uint32_t r = v.u + 0x7fffu + ((v.u >> 16) & 1u);
  return (unsigned short)(r >> 16);
}
static __device__ __forceinline__ float bf2f(unsigned short s){
  union { uint32_t u; float f; } v; v.u = ((uint32_t)s) << 16;
  return v.f;
}
static __device__ __forceinline__ unsigned int pkbf2(float lo, float hi){
  union { __hip_bfloat162 b; unsigned int u; } cv;
  cv.b = __float22bfloat162_rn(make_float2(lo, hi));
  return cv.u;
}

static __device__ __forceinline__ void gl_lds16(const void* gp, void* lp){
  __builtin_amdgcn_global_load_lds(
      (const __attribute__((address_space(1))) unsigned int*)gp,
      (__attribute__((address_space(3))) unsigned int*)lp, 16, 0, 0);
}

// Tiled bf16 weight layout: off(n,k) = ((n>>6)*(K>>6) + (k>>6))*4096 + (n&63)*64 + (k&63)

static __device__ __forceinline__ void conv_emit(
    const float* __restrict__ tile, unsigned short* __restrict__ d,
    int R, int rt, int ct, int tid)
{
  unsigned short* dt = d + ((size_t)ct * (R >> 6) + rt) * 4096;
  #pragma unroll
  for (int it = 0; it < 2; it++){
    int q = tid + it * 256;
    int c = q >> 3, rg = (q & 7) * 8;
    union { bf16x8 v; unsigned int u[4]; } pk;
    #pragma unroll
    for (int k = 0; k < 4; k++)
      pk.u[k] = pkbf2(tile[(rg + 2 * k) * 69 + c], tile[(rg + 2 * k + 1) * 69 + c]);
    *(bf16x8*)(dt + c * 64 + rg) = pk.v;
  }
}

// conv 4-tile: k-tiles rt0..rt0+3 of column-tile ct; all 16 loads issued first.
static __device__ __forceinline__ void conv_tile4(
    const float* __restrict__ s, unsigned short* __restrict__ d,
    int R, int C, int rt0, int ct, int tid, float* t0, float* t1)
{
  const int c0 = ct * 64;
  const int rr = tid >> 4, cc = (tid & 15) * 4;
  float4 v[4][4];
  #pragma unroll
  for (int tdx = 0; tdx < 4; tdx++)
    #pragma unroll
    for (int i = 0; i < 4; i++)
      v[tdx][i] = *(const float4*)(s + (size_t)((rt0 + tdx) * 64 + i * 16 + rr) * C + c0 + cc);
  #pragma unroll
  for (int i = 0; i < 4; i++){
    int r = i * 16 + rr;
    *(float4*)(t0 + r * 69 + cc) = v[0][i];
    *(float4*)(t1 + r * 69 + cc) = v[1][i];
  }
  __syncthreads();
  conv_emit(t0, d, R, rt0 + 0, ct, tid);
  conv_emit(t1, d, R, rt0 + 1, ct, tid);
  __syncthreads();
  #pragma unroll
  for (int i = 0; i < 4; i++){
    int r = i * 16 + rr;
    *(float4*)(t0 + r * 69 + cc) = v[2][i];
    *(float4*)(t1 + r * 69 + cc) = v[3][i];
  }
  __syncthreads();
  conv_emit(t0, d, R, rt0 + 2, ct, tid);
  conv_emit(t1, d, R, rt0 + 3, ct, tid);
}

// ---------------- prep: router (blocks 0..511) + conv of gate_up weights (4-tile blocks) ----------------
__global__ __launch_bounds__(256) void prep_kernel(
    const float* __restrict__ x, const float* __restrict__ gw,
    float* __restrict__ topkw, int* __restrict__ choice,
    unsigned short* __restrict__ xbf,
    const float* __restrict__ wgu, unsigned short* __restrict__ wgu_t,
    const float* __restrict__ sgu, unsigned short* __restrict__ sgu_t)
{
  __shared__ __align__(16) float tiles[2][64 * 69];
  const int tid = threadIdx.x;
  const int bid = blockIdx.x;

  if (bid < 512){
    const int lane = tid & 63;
    const int t = bid * 4 + (tid >> 6);
    float s[NEXP];
    #pragma unroll
    for (int e = 0; e < NEXP; e++) s[e] = 0.f;
    #pragma unroll
    for (int j = 0; j < 8; j++){
      const int off = 128 * j + lane * 2;
      float2 xv = *(const float2*)(x + (size_t)t * HDIM + off);
      ushort2 xs = { f2bf(xv.x), f2bf(xv.y) };
      *(ushort2*)(xbf + (size_t)t * HDIM + off) = xs;
      const float4* g0 = (const float4*)(gw + (size_t)off * NEXP);
      const float4* g1 = (const float4*)(gw + (size_t)(off + 1) * NEXP);
      #pragma unroll
      for (int q = 0; q < 4; q++){
        float4 a = g0[q], b = g1[q];
        s[q * 4 + 0] += xv.x * a.x + xv.y * b.x;
        s[q * 4 + 1] += xv.x * a.y + xv.y * b.y;
        s[q * 4 + 2] += xv.x * a.z + xv.y * b.z;
        s[q * 4 + 3] += xv.x * a.w + xv.y * b.w;
      }
    }
    #pragma unroll
    for (int e = 0; e < NEXP; e++){
      #pragma unroll
      for (int off = 32; off; off >>= 1)
        s[e] += __shfl_xor(s[e], off);
    }
    float sc[NEXP];
    #pragma unroll
    for (int e = 0; e < NEXP; e++) sc[e] = 1.f / (1.f + __expf(-s[e]));
    unsigned mask = 0; float w[TOPK]; int id[TOPK];
    #pragma unroll
    for (int k = 0; k < TOPK; k++){
      float best = -1e30f; int bi = 0;
      #pragma unroll
      for (int e = 0; e < NEXP; e++){
        if (!((mask >> e) & 1u) && sc[e] > best){ best = sc[e]; bi = e; }
      }
      mask |= 1u << bi; id[k] = bi; w[k] = best;
    }
    float inv = 1.f / (w[0] + w[1] + w[2] + w[3]);
    if (lane == 0){
      #pragma unroll
      for (int k = 0; k < TOPK; k++){
        topkw[t * TOPK + k] = w[k] * inv;
        choice[t * TOPK + k] = id[k];
      }
    }
    return;
  }

  int id = bid - 512;
  if (id < 1024){                 // wgu: 16 x [1024][1024]; 4 rt-groups x 16 ct each
    int e = id >> 6, j = id & 63;
    conv_tile4(wgu + (size_t)e * 1048576, wgu_t + (size_t)e * 1048576,
               1024, 1024, (j >> 4) * 4, j & 15, tid, tiles[0], tiles[1]);
  } else {                        // sgu: [1024][2048]; 4 rt-groups x 32 ct
    id -= 1024;
    conv_tile4(sgu, sgu_t, 1024, 2048, (id >> 5) * 4, id & 31, tid, tiles[0], tiles[1]);
  }
}

// ---------------- build per-expert lists deterministically ----------------
__global__ __launch_bounds__(256) void build_lists(
    const int* __restrict__ choice, int* __restrict__ counts, int* __restrict__ lists)
{
  const int e = blockIdx.x;
  const int tid = threadIdx.x;
  __shared__ int scnt[256];
  const int base = tid * 32;
  unsigned m = 0; int local = 0;
  #pragma unroll
  for (int i = 0; i < 32; i++){
    bool hit = (choice[base + i] == e);
    m |= (unsigned)hit << i;
    local += hit;
  }
  scnt[tid] = local;
  __syncthreads();
  int v = local;
  for (int off = 1; off < 256; off <<= 1){
    int add = (tid >= off) ? scnt[tid - off] : 0;
    __syncthreads();
    v += add; scnt[tid] = v;
    __syncthreads();
  }
  int pos = v - local;
  #pragma unroll
  for (int i = 0; i < 32; i++){
    if ((m >> i) & 1u) lists[e * NTOK + pos++] = base + i;
  }
  if (tid == 255) counts[e] = v;
}

// ---------------- gu GEMM (L<768) + conv of down weights (L>=768, 4-tile blocks) ----------------
__global__ __launch_bounds__(256) void gu_plus(
    const unsigned short* __restrict__ xbf, const unsigned short* __restrict__ wgu_t,
    const unsigned short* __restrict__ sgu_t,
    unsigned short* __restrict__ act_r, unsigned short* __restrict__ act_s,
    const int* __restrict__ lists, const int* __restrict__ counts,
    const float* __restrict__ wdn, unsigned short* __restrict__ wdn_t,
    const float* __restrict__ sdn, unsigned short* __restrict__ sdn_t)
{
  __shared__ __align__(16) char smem[35328];
  const int tid = threadIdx.x;
  const int L = blockIdx.x;

  if (L >= 768){
    float* t0 = (float*)smem;
    float* t1 = t0 + 64 * 69;
    int id = L - 768;
    if (id < 512){                // wdn: 16 x [512][1024] (R=K=512); 2 rt-groups x 16 ct each
      int e = id >> 5, j = id & 31;
      conv_tile4(wdn + (size_t)e * 524288, wdn_t + (size_t)e * 524288,
                 512, 1024, (j >> 4) * 4, j & 15, tid, t0, t1);
    } else {                      // sdn: [1024][1024]; 4 rt-groups x 16 ct
      id -= 512;
      conv_tile4(sdn, sdn_t, 1024, 1024, (id >> 4) * 4, id & 15, tid, t0, t1);
    }
    return;
  }

  unsigned short* sA0 = (unsigned short*)smem;
  unsigned short* sA1 = sA0 + 4096;
  unsigned short* sB0 = sA1 + 4096;
  unsigned short* sB1 = sB0 + 4096;
  int* sAid = (int*)(smem + 32768);

  const bool routed = (L < 512);
  int e, mIdx, n0, count, NPAIR, NCH;
  const unsigned short* Bt;
  unsigned short* act;
  if (routed){
    int p = L & 7, t = L >> 3;
    mIdx = t & 3; e = t >> 2; n0 = p * 64;
    count = counts[e]; NPAIR = IR; NCH = 4;
    Bt = wgu_t + (size_t)e * (2 * IR) * HDIM;
    act = act_r;
  } else {
    int v = L - 512;
    e = 0; n0 = (v & 15) * 64; mIdx = v >> 4;
    count = NTOK; NPAIR = ISH; NCH = 16;
    Bt = sgu_t; act = act_s;
  }

  const int wv = tid >> 6, lane = tid & 63, lr = lane & 15, g = lane >> 4;
  const int wm = wv >> 1, wn = wv & 1;

  const unsigned short* bsrc[2];
  #pragma unroll
  for (int it = 0; it < 2; it++){
    int q = tid + it * 256;
    int c = q >> 2, ko = (q & 3) * 8;
    int grp = c >> 5, within = c & 31;
    int grow = n0 + (grp >> 1) * 32 + within + ((grp & 1) ? NPAIR : 0);
    bsrc[it] = Bt + ((size_t)(grow >> 6) * (HDIM >> 6)) * 4096 + ((grow & 63) << 6) + ko;
  }

  for (int mt = mIdx; mt * 128 < count; mt += NCH){
    const int m0 = mt * 128;
    __syncthreads();
    if (tid < 128){
      int idx = m0 + tid;
      int aid;
      if (routed) aid = (idx < count) ? lists[e * NTOK + idx] : lists[e * NTOK];
      else        aid = idx;
      sAid[tid] = aid;
    }
    __syncthreads();
    const unsigned short* asrc[2];
    #pragma unroll
    for (int it = 0; it < 2; it++){
      int q = tid + it * 256;
      int r = q >> 2, ko = (q & 3) * 8;
      int aid = sAid[r];
      int tok = routed ? (aid >> 2) : aid;
      asrc[it] = xbf + (size_t)tok * HDIM + ko;
    }

    const f32x4 z4 = {0.f, 0.f, 0.f, 0.f};
    f32x4 acc[4][4];
    #pragma unroll
    for (int i = 0; i < 4; i++)
      #pragma unroll
      for (int j = 0; j < 4; j++) acc[i][j] = z4;

    for (int k0 = 0; k0 < HDIM; k0 += 64){
      const size_t bk = (size_t)k0 * 64;
      #pragma unroll
      for (int it = 0; it < 2; it++){
        gl_lds16(asrc[it] + k0,       sA0 + (tid + it * 256) * 8);
        gl_lds16(asrc[it] + k0 + 32,  sA1 + (tid + it * 256) * 8);
        gl_lds16(bsrc[it] + bk,       sB0 + (tid + it * 256) * 8);
        gl_lds16(bsrc[it] + bk + 32,  sB1 + (tid + it * 256) * 8);
      }
      __syncthreads();
      #pragma unroll
      for (int h = 0; h < 2; h++){
        const unsigned short* sAh = h ? sA1 : sA0;
        const unsigned short* sBh = h ? sB1 : sB0;
        bf16x8 af[4], bfr[4];
        #pragma unroll
        for (int i = 0; i < 4; i++){
          af[i]  = *(const bf16x8*)(sAh + (wm * 64 + i * 16 + lr) * 32 + g * 8);
          bfr[i] = *(const bf16x8*)(sBh + (wn * 64 + i * 16 + lr) * 32 + g * 8);
        }
        #pragma unroll
        for (int mi = 0; mi < 4; mi++)
          #pragma unroll
          for (int ni = 0; ni < 4; ni++)
            acc[mi][ni] = __builtin_amdgcn_mfma_f32_16x16x32_bf16(af[mi], bfr[ni], acc[mi][ni], 0, 0, 0);
      }
      __syncthreads();
    }

    #pragma unroll
    for (int mi = 0; mi < 4; mi++){
      #pragma unroll
      for (int r = 0; r < 4; r++){
        int row = wm * 64 + mi * 16 + g * 4 + r;
        if (routed && m0 + row >= count) continue;
        int aid = sAid[row];
        size_t arow = (size_t)aid * NPAIR;
        #pragma unroll
        for (int ni = 0; ni < 2; ni++){
          float gv = acc[mi][ni][r];
          float uv = acc[mi][ni + 2][r];
          float a = gv / (1.f + __expf(-gv)) * uv;
          act[arow + n0 + wn * 32 + ni * 16 + lr] = f2bf(a);
        }
      }
    }
  }
}

// ---------------- down GEMM: routed (512) + shared K-split (256) ----------------
__global__ __launch_bounds__(256) void down_gemm(
    const unsigned short* __restrict__ act_r, const unsigned short* __restrict__ act_s,
    const unsigned short* __restrict__ wdn_t, const unsigned short* __restrict__ sdn_t,
    float* __restrict__ shout, unsigned short* __restrict__ downout,
    const int* __restrict__ lists, const int* __restrict__ counts)
{
  __shared__ unsigned short sA[2][128 * 32];
  __shared__ unsigned short sB[2][128 * 32];
  __shared__ int sAid[128];

  const int tid = threadIdx.x;
  const int L = blockIdx.x;
  const bool routed = (L < 512);
  int e, mIdx, n0, count, kBeg, kEnd, NCH, KT;
  const unsigned short* Bt;
  const unsigned short* Ab;
  float* outp = nullptr;
  if (routed){
    int p = L & 7, t = L >> 3;
    mIdx = t & 3; e = t >> 2; n0 = p * 128;
    count = counts[e]; kBeg = 0; kEnd = IR; KT = IR; NCH = 4;
    Bt = wdn_t + (size_t)e * HDIM * IR;
    Ab = act_r;
  } else {
    int v = L - 512;
    int half = v >> 7, w = v & 127;
    e = 0; n0 = (w & 7) * 128; mIdx = w >> 3;
    count = NTOK; kBeg = half * 512; kEnd = kBeg + 512; KT = ISH; NCH = 16;
    Bt = sdn_t; Ab = act_s;
    outp = shout + (size_t)half * 2097152;
  }

  const int wv = tid >> 6, lane = tid & 63, lr = lane & 15, g = lane >> 4;
  const int wm = wv >> 1, wn = wv & 1;

  const unsigned short* bsrc[2];
  #pragma unroll
  for (int it = 0; it < 2; it++){
    int q = tid + it * 256;
    int c = q >> 2, ko = (q & 3) * 8;
    int grow = n0 + c;
    bsrc[it] = Bt + ((size_t)(grow >> 6) * (KT >> 6)) * 4096 + ((grow & 63) << 6) + ko;
  }

  for (int mt = mIdx; mt * 128 < count; mt += NCH){
    const int m0 = mt * 128;
    __syncthreads();
    if (tid < 128){
      int idx = m0 + tid;
      int aid;
      if (routed) aid = (idx < count) ? lists[e * NTOK + idx] : lists[e * NTOK];
      else        aid = idx;
      sAid[tid] = aid;
    }
    __syncthreads();
    const unsigned short* asrc[2];
    #pragma unroll
    for (int it = 0; it < 2; it++){
      int q = tid + it * 256;
      int r = q >> 2, ko = (q & 3) * 8;
      asrc[it] = Ab + (size_t)sAid[r] * KT + ko;
    }

    const f32x4 z4 = {0.f, 0.f, 0.f, 0.f};
    f32x4 acc[4][4];
    #pragma unroll
    for (int i = 0; i < 4; i++)
      #pragma unroll
      for (int j = 0; j < 4; j++) acc[i][j] = z4;

    for (int k0 = kBeg; k0 < kEnd; k0 += 64){
      const size_t bk = (size_t)k0 * 64;
      #pragma unroll
      for (int it = 0; it < 2; it++){
        gl_lds16(asrc[it] + k0,       sA[0] + (tid + it * 256) * 8);
        gl_lds16(asrc[it] + k0 + 32,  sA[1] + (tid + it * 256) * 8);
        gl_lds16(bsrc[it] + bk,       sB[0] + (tid + it * 256) * 8);
        gl_lds16(bsrc[it] + bk + 32,  sB[1] + (tid + it * 256) * 8);
      }
      __syncthreads();
      #pragma unroll
      for (int h = 0; h < 2; h++){
        bf16x8 af[4], bfr[4];
        #pragma unroll
        for (int i = 0; i < 4; i++){
          af[i]  = *(const bf16x8*)(sA[h] + (wm * 64 + i * 16 + lr) * 32 + g * 8);
          bfr[i] = *(const bf16x8*)(sB[h] + (wn * 64 + i * 16 + lr) * 32 + g * 8);
        }
        #pragma unroll
        for (int mi = 0; mi < 4; mi++)
          #pragma unroll
          for (int ni = 0; ni < 4; ni++)
            acc[mi][ni] = __builtin_amdgcn_mfma_f32_16x16x32_bf16(af[mi], bfr[ni], acc[mi][ni], 0, 0, 0);
      }
      __syncthreads();
    }

    #pragma unroll
    for (int mi = 0; mi < 4; mi++){
      #pragma unroll
      for (int r = 0; r < 4; r++){
        int row = wm * 64 + mi * 16 + g * 4 + r;
        if (m0 + row >= count) continue;
        int aid = sAid[row];
        size_t orow = (size_t)aid * HDIM;
        if (routed){
          #pragma unroll
          for (int ni = 0; ni < 4; ni++)
            downout[orow + n0 + wn * 64 + ni * 16 + lr] = f2bf(acc[mi][ni][r]);
        } else {
          #pragma unroll
          for (int ni = 0; ni < 4; ni++)
            outp[orow + n0 + wn * 64 + ni * 16 + lr] = acc[mi][ni][r];
        }
      }
    }
  }
}

// ---------------- combine (pure store): out = shout0 + shout1 + RSCALE * sum_k w_k * down_k ----------------
__global__ __launch_bounds__(256) void combine_kernel(
    float* __restrict__ out, const float* __restrict__ shout,
    const unsigned short* __restrict__ downout, const float* __restrict__ topkw)
{
  const int idx = blockIdx.x * 256 + threadIdx.x;
  const int t = idx >> 8;
  const int c4 = (idx & 255) * 4;
  float4 o0 = *(const float4*)(shout + (size_t)t * HDIM + c4);
  float4 o1 = *(const float4*)(shout + 2097152 + (size_t)t * HDIM + c4);
  float r0 = 0.f, r1 = 0.f, r2 = 0.f, r3 = 0.f;
  #pragma unroll
  for (int k = 0; k < TOPK; k++){
    float w = topkw[t * TOPK + k];
    const ushort4 dv = *(const ushort4*)(downout + (size_t)(t * TOPK + k) * HDIM + c4);
    r0 += w * bf2f(dv.x); r1 += w * bf2f(dv.y);
    r2 += w * bf2f(dv.z); r3 += w * bf2f(dv.w);
  }
  float4 o;
  o.x = o0.x + o1.x + RSCALE * r0;
  o.y = o0.y + o1.y + RSCALE * r1;
  o.z = o0.z + o1.z + RSCALE * r2;
  o.w = o0.w + o1.w + RSCALE * r3;
  *(float4*)(out + (size_t)t * HDIM + c4) = o;
}

extern "C" void kernel_launch(void* const* d_in, const int* in_sizes, int n_in,
                              void* d_out, int out_size, void* d_ws, size_t ws_size,
                              hipStream_t stream) {
  const float* x   = (const float*)d_in[0];
  const float* gw  = (const float*)d_in[1];
  const float* wgu = (const float*)d_in[2];
  const float* wdn = (const float*)d_in[3];
  const float* sgu = (const float*)d_in[4];
  const float* sdn = (const float*)d_in[5];
  float* out = (float*)d_out;

  char* ws = (char*)d_ws;
  float* topkw = (float*)(ws + 0);                                        // 32 KB
  int* choice  = (int*)(ws + 32768);                                      // 32 KB
  int* counts  = (int*)(ws + 65536);                                      // 256 B
  int* lists   = (int*)(ws + 65792);                                      // 128 KB -> 196864
  unsigned short* xbf   = (unsigned short*)(ws + 197120);                 // 4 MB
  unsigned short* wgu_t = (unsigned short*)(ws + 197120 + 4194304ull);    // 32 MB
  unsigned short* wdn_t = (unsigned short*)(ws + 197120 + 37748736ull);   // 16 MB
  unsigned short* sgu_t = (unsigned short*)(ws + 197120 + 54525952ull);   // 4 MB
  unsigned short* sdn_t = (unsigned short*)(ws + 197120 + 58720256ull);   // 2 MB
  unsigned short* act_r = (unsigned short*)(ws + 197120 + 60817408ull);   // 8 MB
  unsigned short* act_s = (unsigned short*)(ws + 197120 + 69206016ull);   // 4 MB -> ~73.6 MB total
  // downout (16 MB) + shout0/1 (16 MB) alias wgu_t (32 MB): wgu_t's last read is gu_plus,
  // which completes before down_gemm writes (same stream); prep rewrites wgu_t each replay.
  unsigned short* downout = wgu_t;
  float*          shout   = (float*)((char*)wgu_t + 16777216ull);

  prep_kernel<<<512 + 1152, 256, 0, stream>>>(x, gw, topkw, choice, xbf,
                                              wgu, wgu_t, sgu, sgu_t);
  build_lists<<<NEXP, 256, 0, stream>>>(choice, counts, lists);
  gu_plus<<<768 + 576, 256, 0, stream>>>(xbf, wgu_t, sgu_t, act_r, act_s,
                                         lists, counts, wdn, wdn_t, sdn, sdn_t);
  down_gemm<<<768, 256, 0, stream>>>(act_r, act_s, wdn_t, sdn_t, shout, downout, lists, counts);
  combine_kernel<<<(NTOK * HDIM / 4) / 256, 256, 0, stream>>>(out, shout, downout, topkw);
}

// Round 23
// 125.005 us; speedup vs baseline: 1.3085x; 1.3085x over previous
//
#include <hip/hip_runtime.h>
#include <hip/hip_bf16.h>
#include <stdint.h>

#define NTOK 2048
#define HDIM 1024
#define NEXP 16
#define TOPK 4
#define IR   512
#define ISH  1024
#define RSCALE 2.5f

typedef short bf16x4 __attribute__((ext_vector_type(4)));
typedef short bf16x8 __attribute__((ext_vector_type(8)));
typedef float f32x4  __attribute__((ext_vector_type(4)));

static __device__ __forceinline__ unsigned short f2bf(float f){
  union { float fv; uint32_t u; } v; v.fv = f;
  uint32_t r = v.u + 0x7fffu + ((v.u >> 16) & 1u);
  return (unsigned short)(r >> 16);
}
static __device__ __forceinline__ float bf2f(unsigned short s){
  union { uint32_t u; float f; } v; v.u = ((uint32_t)s) << 16;
  return v.f;
}
static __device__ __forceinline__ unsigned int pkbf2(float lo, float hi){
  union { __hip_bfloat162 b; unsigned int u; } cv;
  cv.b = __float22bfloat162_rn(make_float2(lo, hi));
  return cv.u;
}

static __device__ __forceinline__ void gl_lds16(const void* gp, void* lp){
  __builtin_amdgcn_global_load_lds(
      (const __attribute__((address_space(1))) unsigned int*)gp,
      (__attribute__((address_space(3))) unsigned int*)lp, 16, 0, 0);
}

// Tiled bf16 weight layout: off(n,k) = ((n>>6)*(K>>6) + (k>>6))*4096 + (n&63)*64 + (k&63)

// conv 2-tile: k-tiles rt0, rt0+1 of column-tile ct; all 8 loads issued first.
static __device__ __forceinline__ void conv_tile2(
    const float* __restrict__ s, unsigned short* __restrict__ d,
    int R, int C, int rt0, int ct, int tid, float* t0, float* t1)
{
  const int c0 = ct * 64;
  const int rr = tid >> 4, cc = (tid & 15) * 4;
  float4 v0[4], v1[4];
  #pragma unroll
  for (int i = 0; i < 4; i++){
    int r = i * 16 + rr;
    v0[i] = *(const float4*)(s + (size_t)(rt0 * 64 + r) * C + c0 + cc);
    v1[i] = *(const float4*)(s + (size_t)(rt0 * 64 + 64 + r) * C + c0 + cc);
  }
  #pragma unroll
  for (int i = 0; i < 4; i++){
    int r = i * 16 + rr;
    *(float4*)(t0 + r * 69 + cc) = v0[i];
    *(float4*)(t1 + r * 69 + cc) = v1[i];
  }
  __syncthreads();
  #pragma unroll
  for (int h = 0; h < 2; h++){
    const float* tile = h ? t1 : t0;
    unsigned short* dt = d + ((size_t)ct * (R >> 6) + rt0 + h) * 4096;
    #pragma unroll
    for (int it = 0; it < 2; it++){
      int q = tid + it * 256;
      int c = q >> 3, rg = (q & 7) * 8;
      union { bf16x8 v; unsigned int u[4]; } pk;
      #pragma unroll
      for (int k = 0; k < 4; k++)
        pk.u[k] = pkbf2(tile[(rg + 2 * k) * 69 + c], tile[(rg + 2 * k + 1) * 69 + c]);
      *(bf16x8*)(dt + c * 64 + rg) = pk.v;
    }
  }
}

// ---------------- prep: router (blocks 0..511) + conv of gate_up weights (2-tile blocks) ----------------
__global__ __launch_bounds__(256) void prep_kernel(
    const float* __restrict__ x, const float* __restrict__ gw,
    float* __restrict__ topkw, int* __restrict__ choice,
    unsigned short* __restrict__ xbf,
    const float* __restrict__ wgu, unsigned short* __restrict__ wgu_t,
    const float* __restrict__ sgu, unsigned short* __restrict__ sgu_t)
{
  __shared__ __align__(16) float tiles[2][64 * 69];
  const int tid = threadIdx.x;
  const int bid = blockIdx.x;

  if (bid < 512){
    const int lane = tid & 63;
    const int t = bid * 4 + (tid >> 6);
    float s[NEXP];
    #pragma unroll
    for (int e = 0; e < NEXP; e++) s[e] = 0.f;
    #pragma unroll
    for (int j = 0; j < 8; j++){
      const int off = 128 * j + lane * 2;
      float2 xv = *(const float2*)(x + (size_t)t * HDIM + off);
      ushort2 xs = { f2bf(xv.x), f2bf(xv.y) };
      *(ushort2*)(xbf + (size_t)t * HDIM + off) = xs;
      const float4* g0 = (const float4*)(gw + (size_t)off * NEXP);
      const float4* g1 = (const float4*)(gw + (size_t)(off + 1) * NEXP);
      #pragma unroll
      for (int q = 0; q < 4; q++){
        float4 a = g0[q], b = g1[q];
        s[q * 4 + 0] += xv.x * a.x + xv.y * b.x;
        s[q * 4 + 1] += xv.x * a.y + xv.y * b.y;
        s[q * 4 + 2] += xv.x * a.z + xv.y * b.z;
        s[q * 4 + 3] += xv.x * a.w + xv.y * b.w;
      }
    }
    #pragma unroll
    for (int e = 0; e < NEXP; e++){
      #pragma unroll
      for (int off = 32; off; off >>= 1)
        s[e] += __shfl_xor(s[e], off);
    }
    float sc[NEXP];
    #pragma unroll
    for (int e = 0; e < NEXP; e++) sc[e] = 1.f / (1.f + __expf(-s[e]));
    unsigned mask = 0; float w[TOPK]; int id[TOPK];
    #pragma unroll
    for (int k = 0; k < TOPK; k++){
      float best = -1e30f; int bi = 0;
      #pragma unroll
      for (int e = 0; e < NEXP; e++){
        if (!((mask >> e) & 1u) && sc[e] > best){ best = sc[e]; bi = e; }
      }
      mask |= 1u << bi; id[k] = bi; w[k] = best;
    }
    float inv = 1.f / (w[0] + w[1] + w[2] + w[3]);
    if (lane == 0){
      #pragma unroll
      for (int k = 0; k < TOPK; k++){
        topkw[t * TOPK + k] = w[k] * inv;
        choice[t * TOPK + k] = id[k];
      }
    }
    return;
  }

  int id = bid - 512;
  if (id < 2048){                 // wgu: 16 x [1024][1024], 128 tile-pairs each
    int e = id >> 7, j = id & 127;
    conv_tile2(wgu + (size_t)e * 1048576, wgu_t + (size_t)e * 1048576,
               1024, 1024, (j >> 4) * 2, j & 15, tid, tiles[0], tiles[1]);
  } else {                        // sgu: [1024][2048], 256 tile-pairs
    id -= 2048;
    conv_tile2(sgu, sgu_t, 1024, 2048, (id >> 5) * 2, id & 31, tid, tiles[0], tiles[1]);
  }
}

// ---------------- build per-expert lists deterministically ----------------
__global__ __launch_bounds__(256) void build_lists(
    const int* __restrict__ choice, int* __restrict__ counts, int* __restrict__ lists)
{
  const int e = blockIdx.x;
  const int tid = threadIdx.x;
  __shared__ int scnt[256];
  const int base = tid * 32;
  unsigned m = 0; int local = 0;
  #pragma unroll
  for (int i = 0; i < 32; i++){
    bool hit = (choice[base + i] == e);
    m |= (unsigned)hit << i;
    local += hit;
  }
  scnt[tid] = local;
  __syncthreads();
  int v = local;
  for (int off = 1; off < 256; off <<= 1){
    int add = (tid >= off) ? scnt[tid - off] : 0;
    __syncthreads();
    v += add; scnt[tid] = v;
    __syncthreads();
  }
  int pos = v - local;
  #pragma unroll
  for (int i = 0; i < 32; i++){
    if ((m >> i) & 1u) lists[e * NTOK + pos++] = base + i;
  }
  if (tid == 255) counts[e] = v;
}

// ---------------- gu GEMM (L<768) + conv of down weights (L>=768, 2-tile blocks) ----------------
__global__ __launch_bounds__(256) void gu_plus(
    const unsigned short* __restrict__ xbf, const unsigned short* __restrict__ wgu_t,
    const unsigned short* __restrict__ sgu_t,
    unsigned short* __restrict__ act_r, unsigned short* __restrict__ act_s,
    const int* __restrict__ lists, const int* __restrict__ counts,
    const float* __restrict__ wdn, unsigned short* __restrict__ wdn_t,
    const float* __restrict__ sdn, unsigned short* __restrict__ sdn_t)
{
  __shared__ __align__(16) char smem[35328];
  const int tid = threadIdx.x;
  const int L = blockIdx.x;

  if (L >= 768){
    float* t0 = (float*)smem;
    float* t1 = t0 + 64 * 69;
    int id = L - 768;
    if (id < 1024){               // wdn: 16 x [512][1024] (R=K=512), 64 tile-pairs each
      int e = id >> 6, j = id & 63;
      conv_tile2(wdn + (size_t)e * 524288, wdn_t + (size_t)e * 524288,
                 512, 1024, (j >> 4) * 2, j & 15, tid, t0, t1);
    } else {                      // sdn: [1024][1024], 128 tile-pairs
      id -= 1024;
      conv_tile2(sdn, sdn_t, 1024, 1024, (id >> 4) * 2, id & 15, tid, t0, t1);
    }
    return;
  }

  unsigned short* sA0 = (unsigned short*)smem;
  unsigned short* sA1 = sA0 + 4096;
  unsigned short* sB0 = sA1 + 4096;
  unsigned short* sB1 = sB0 + 4096;
  int* sAid = (int*)(smem + 32768);

  const bool routed = (L < 512);
  int e, mIdx, n0, count, NPAIR, NCH;
  const unsigned short* Bt;
  unsigned short* act;
  if (routed){
    int p = L & 7, t = L >> 3;
    mIdx = t & 3; e = t >> 2; n0 = p * 64;
    count = counts[e]; NPAIR = IR; NCH = 4;
    Bt = wgu_t + (size_t)e * (2 * IR) * HDIM;
    act = act_r;
  } else {
    int v = L - 512;
    e = 0; n0 = (v & 15) * 64; mIdx = v >> 4;
    count = NTOK; NPAIR = ISH; NCH = 16;
    Bt = sgu_t; act = act_s;
  }

  const int wv = tid >> 6, lane = tid & 63, lr = lane & 15, g = lane >> 4;
  const int wm = wv >> 1, wn = wv & 1;

  const unsigned short* bsrc[2];
  #pragma unroll
  for (int it = 0; it < 2; it++){
    int q = tid + it * 256;
    int c = q >> 2, ko = (q & 3) * 8;
    int grp = c >> 5, within = c & 31;
    int grow = n0 + (grp >> 1) * 32 + within + ((grp & 1) ? NPAIR : 0);
    bsrc[it] = Bt + ((size_t)(grow >> 6) * (HDIM >> 6)) * 4096 + ((grow & 63) << 6) + ko;
  }

  for (int mt = mIdx; mt * 128 < count; mt += NCH){
    const int m0 = mt * 128;
    __syncthreads();
    if (tid < 128){
      int idx = m0 + tid;
      int aid;
      if (routed) aid = (idx < count) ? lists[e * NTOK + idx] : lists[e * NTOK];
      else        aid = idx;
      sAid[tid] = aid;
    }
    __syncthreads();
    const unsigned short* asrc[2];
    #pragma unroll
    for (int it = 0; it < 2; it++){
      int q = tid + it * 256;
      int r = q >> 2, ko = (q & 3) * 8;
      int aid = sAid[r];
      int tok = routed ? (aid >> 2) : aid;
      asrc[it] = xbf + (size_t)tok * HDIM + ko;
    }

    const f32x4 z4 = {0.f, 0.f, 0.f, 0.f};
    f32x4 acc[4][4];
    #pragma unroll
    for (int i = 0; i < 4; i++)
      #pragma unroll
      for (int j = 0; j < 4; j++) acc[i][j] = z4;

    for (int k0 = 0; k0 < HDIM; k0 += 64){
      const size_t bk = (size_t)k0 * 64;
      #pragma unroll
      for (int it = 0; it < 2; it++){
        gl_lds16(asrc[it] + k0,       sA0 + (tid + it * 256) * 8);
        gl_lds16(asrc[it] + k0 + 32,  sA1 + (tid + it * 256) * 8);
        gl_lds16(bsrc[it] + bk,       sB0 + (tid + it * 256) * 8);
        gl_lds16(bsrc[it] + bk + 32,  sB1 + (tid + it * 256) * 8);
      }
      __syncthreads();
      #pragma unroll
      for (int h = 0; h < 2; h++){
        const unsigned short* sAh = h ? sA1 : sA0;
        const unsigned short* sBh = h ? sB1 : sB0;
        bf16x8 af[4], bfr[4];
        #pragma unroll
        for (int i = 0; i < 4; i++){
          af[i]  = *(const bf16x8*)(sAh + (wm * 64 + i * 16 + lr) * 32 + g * 8);
          bfr[i] = *(const bf16x8*)(sBh + (wn * 64 + i * 16 + lr) * 32 + g * 8);
        }
        #pragma unroll
        for (int mi = 0; mi < 4; mi++)
          #pragma unroll
          for (int ni = 0; ni < 4; ni++)
            acc[mi][ni] = __builtin_amdgcn_mfma_f32_16x16x32_bf16(af[mi], bfr[ni], acc[mi][ni], 0, 0, 0);
      }
      __syncthreads();
    }

    #pragma unroll
    for (int mi = 0; mi < 4; mi++){
      #pragma unroll
      for (int r = 0; r < 4; r++){
        int row = wm * 64 + mi * 16 + g * 4 + r;
        if (routed && m0 + row >= count) continue;
        int aid = sAid[row];
        size_t arow = (size_t)aid * NPAIR;
        #pragma unroll
        for (int ni = 0; ni < 2; ni++){
          float gv = acc[mi][ni][r];
          float uv = acc[mi][ni + 2][r];
          float a = gv / (1.f + __expf(-gv)) * uv;
          act[arow + n0 + wn * 32 + ni * 16 + lr] = f2bf(a);
        }
      }
    }
  }
}

// ---------------- down GEMM: routed (512) + shared K-split (256) ----------------
__global__ __launch_bounds__(256) void down_gemm(
    const unsigned short* __restrict__ act_r, const unsigned short* __restrict__ act_s,
    const unsigned short* __restrict__ wdn_t, const unsigned short* __restrict__ sdn_t,
    float* __restrict__ shout, unsigned short* __restrict__ downout,
    const int* __restrict__ lists, const int* __restrict__ counts)
{
  __shared__ unsigned short sA[2][128 * 32];
  __shared__ unsigned short sB[2][128 * 32];
  __shared__ int sAid[128];

  const int tid = threadIdx.x;
  const int L = blockIdx.x;
  const bool routed = (L < 512);
  int e, mIdx, n0, count, kBeg, kEnd, NCH, KT;
  const unsigned short* Bt;
  const unsigned short* Ab;
  float* outp = nullptr;
  if (routed){
    int p = L & 7, t = L >> 3;
    mIdx = t & 3; e = t >> 2; n0 = p * 128;
    count = counts[e]; kBeg = 0; kEnd = IR; KT = IR; NCH = 4;
    Bt = wdn_t + (size_t)e * HDIM * IR;
    Ab = act_r;
  } else {
    int v = L - 512;
    int half = v >> 7, w = v & 127;
    e = 0; n0 = (w & 7) * 128; mIdx = w >> 3;
    count = NTOK; kBeg = half * 512; kEnd = kBeg + 512; KT = ISH; NCH = 16;
    Bt = sdn_t; Ab = act_s;
    outp = shout + (size_t)half * 2097152;
  }

  const int wv = tid >> 6, lane = tid & 63, lr = lane & 15, g = lane >> 4;
  const int wm = wv >> 1, wn = wv & 1;

  const unsigned short* bsrc[2];
  #pragma unroll
  for (int it = 0; it < 2; it++){
    int q = tid + it * 256;
    int c = q >> 2, ko = (q & 3) * 8;
    int grow = n0 + c;
    bsrc[it] = Bt + ((size_t)(grow >> 6) * (KT >> 6)) * 4096 + ((grow & 63) << 6) + ko;
  }

  for (int mt = mIdx; mt * 128 < count; mt += NCH){
    const int m0 = mt * 128;
    __syncthreads();
    if (tid < 128){
      int idx = m0 + tid;
      int aid;
      if (routed) aid = (idx < count) ? lists[e * NTOK + idx] : lists[e * NTOK];
      else        aid = idx;
      sAid[tid] = aid;
    }
    __syncthreads();
    const unsigned short* asrc[2];
    #pragma unroll
    for (int it = 0; it < 2; it++){
      int q = tid + it * 256;
      int r = q >> 2, ko = (q & 3) * 8;
      asrc[it] = Ab + (size_t)sAid[r] * KT + ko;
    }

    const f32x4 z4 = {0.f, 0.f, 0.f, 0.f};
    f32x4 acc[4][4];
    #pragma unroll
    for (int i = 0; i < 4; i++)
      #pragma unroll
      for (int j = 0; j < 4; j++) acc[i][j] = z4;

    for (int k0 = kBeg; k0 < kEnd; k0 += 64){
      const size_t bk = (size_t)k0 * 64;
      #pragma unroll
      for (int it = 0; it < 2; it++){
        gl_lds16(asrc[it] + k0,       sA[0] + (tid + it * 256) * 8);
        gl_lds16(asrc[it] + k0 + 32,  sA[1] + (tid + it * 256) * 8);
        gl_lds16(bsrc[it] + bk,       sB[0] + (tid + it * 256) * 8);
        gl_lds16(bsrc[it] + bk + 32,  sB[1] + (tid + it * 256) * 8);
      }
      __syncthreads();
      #pragma unroll
      for (int h = 0; h < 2; h++){
        bf16x8 af[4], bfr[4];
        #pragma unroll
        for (int i = 0; i < 4; i++){
          af[i]  = *(const bf16x8*)(sA[h] + (wm * 64 + i * 16 + lr) * 32 + g * 8);
          bfr[i] = *(const bf16x8*)(sB[h] + (wn * 64 + i * 16 + lr) * 32 + g * 8);
        }
        #pragma unroll
        for (int mi = 0; mi < 4; mi++)
          #pragma unroll
          for (int ni = 0; ni < 4; ni++)
            acc[mi][ni] = __builtin_amdgcn_mfma_f32_16x16x32_bf16(af[mi], bfr[ni], acc[mi][ni], 0, 0, 0);
      }
      __syncthreads();
    }

    #pragma unroll
    for (int mi = 0; mi < 4; mi++){
      #pragma unroll
      for (int r = 0; r < 4; r++){
        int row = wm * 64 + mi * 16 + g * 4 + r;
        if (m0 + row >= count) continue;
        int aid = sAid[row];
        size_t orow = (size_t)aid * HDIM;
        if (routed){
          #pragma unroll
          for (int ni = 0; ni < 4; ni++)
            downout[orow + n0 + wn * 64 + ni * 16 + lr] = f2bf(acc[mi][ni][r]);
        } else {
          #pragma unroll
          for (int ni = 0; ni < 4; ni++)
            outp[orow + n0 + wn * 64 + ni * 16 + lr] = acc[mi][ni][r];
        }
      }
    }
  }
}

// ---------------- combine (pure store): out = shout0 + shout1 + RSCALE * sum_k w_k * down_k ----------------
__global__ __launch_bounds__(256) void combine_kernel(
    float* __restrict__ out, const float* __restrict__ shout,
    const unsigned short* __restrict__ downout, const float* __restrict__ topkw)
{
  const int idx = blockIdx.x * 256 + threadIdx.x;
  const int t = idx >> 8;
  const int c4 = (idx & 255) * 4;
  float4 o0 = *(const float4*)(shout + (size_t)t * HDIM + c4);
  float4 o1 = *(const float4*)(shout + 2097152 + (size_t)t * HDIM + c4);
  float r0 = 0.f, r1 = 0.f, r2 = 0.f, r3 = 0.f;
  #pragma unroll
  for (int k = 0; k < TOPK; k++){
    float w = topkw[t * TOPK + k];
    const ushort4 dv = *(const ushort4*)(downout + (size_t)(t * TOPK + k) * HDIM + c4);
    r0 += w * bf2f(dv.x); r1 += w * bf2f(dv.y);
    r2 += w * bf2f(dv.z); r3 += w * bf2f(dv.w);
  }
  float4 o;
  o.x = o0.x + o1.x + RSCALE * r0;
  o.y = o0.y + o1.y + RSCALE * r1;
  o.z = o0.z + o1.z + RSCALE * r2;
  o.w = o0.w + o1.w + RSCALE * r3;
  *(float4*)(out + (size_t)t * HDIM + c4) = o;
}

extern "C" void kernel_launch(void* const* d_in, const int* in_sizes, int n_in,
                              void* d_out, int out_size, void* d_ws, size_t ws_size,
                              hipStream_t stream) {
  const float* x   = (const float*)d_in[0];
  const float* gw  = (const float*)d_in[1];
  const float* wgu = (const float*)d_in[2];
  const float* wdn = (const float*)d_in[3];
  const float* sgu = (const float*)d_in[4];
  const float* sdn = (const float*)d_in[5];
  float* out = (float*)d_out;

  char* ws = (char*)d_ws;
  float* topkw = (float*)(ws + 0);                                        // 32 KB
  int* choice  = (int*)(ws + 32768);                                      // 32 KB
  int* counts  = (int*)(ws + 65536);                                      // 256 B
  int* lists   = (int*)(ws + 65792);                                      // 128 KB -> 196864
  unsigned short* xbf   = (unsigned short*)(ws + 197120);                 // 4 MB
  unsigned short* wgu_t = (unsigned short*)(ws + 197120 + 4194304ull);    // 32 MB
  unsigned short* wdn_t = (unsigned short*)(ws + 197120 + 37748736ull);   // 16 MB
  unsigned short* sgu_t = (unsigned short*)(ws + 197120 + 54525952ull);   // 4 MB
  unsigned short* sdn_t = (unsigned short*)(ws + 197120 + 58720256ull);   // 2 MB
  unsigned short* act_r = (unsigned short*)(ws + 197120 + 60817408ull);   // 8 MB
  unsigned short* act_s = (unsigned short*)(ws + 197120 + 69206016ull);   // 4 MB -> ~73.6 MB total
  // downout (16 MB) + shout0/1 (16 MB) alias wgu_t (32 MB): wgu_t's last read is gu_plus,
  // which completes before down_gemm writes (same stream); prep rewrites wgu_t each replay.
  unsigned short* downout = wgu_t;
  float*          shout   = (float*)((char*)wgu_t + 16777216ull);

  prep_kernel<<<512 + 2304, 256, 0, stream>>>(x, gw, topkw, choice, xbf,
                                              wgu, wgu_t, sgu, sgu_t);
  build_lists<<<NEXP, 256, 0, stream>>>(choice, counts, lists);
  gu_plus<<<768 + 1152, 256, 0, stream>>>(xbf, wgu_t, sgu_t, act_r, act_s,
                                          lists, counts, wdn, wdn_t, sdn, sdn_t);
  down_gemm<<<768, 256, 0, stream>>>(act_r, act_s, wdn_t, sdn_t, shout, downout, lists, counts);
  combine_kernel<<<(NTOK * HDIM / 4) / 256, 256, 0, stream>>>(out, shout, downout, topkw);
}